// Round 9
// baseline (1378.281 us; speedup 1.0000x reference)
//
#include <hip/hip_runtime.h>

// SSIM 3D loss: pred/target f32 [4,1,64,192,192], scalar 1 - mean(ssim_map).
// v8: fused kernel, register D-accumulator (no LDS ring, no fp16).
//     Block = 16x16 px tile x D-segment x batch. March along D:
//       stage 26x26 halo -> W-blur (float4 interm) -> H-blur into per-thread
//       registers -> 11-slot register accumulator update (literal slots;
//       seg bases -5 and 28 are congruent mod 11 so slot literals are
//       shared) -> guarded SSIM emit. Invalid planes skip the pipeline.
//     2 barriers/plane. Full fp32. finalize sums 1152 partials.

#define D_DIM 64
#define H_DIM 192
#define W_DIM 192
#define SLICE (H_DIM * W_DIM)   // 36864
#define VOL   (D_DIM * SLICE)   // 2359296
#define NB    4
#define KS    11
#define RAD   5
#define TH    16
#define TW    16
#define HALO  26                // TH + 2*RAD
#define SPITCH 27               // staging pitch (floats)
#define IAP   17                // iA pitch (float4)
#define IBP   18                // iB pitch (floats)
#define C1F   (0.01f * 0.01f)
#define C2F   (0.03f * 0.03f)

__device__ __forceinline__ void make_window(float* g) {
    float s = 0.f;
#pragma unroll
    for (int i = 0; i < KS; ++i) {
        float c = (float)(i - RAD);
        g[i] = expf(-(c * c) * (1.0f / 4.5f));  // 2*sigma^2 = 4.5
        s += g[i];
    }
    float inv = 1.0f / s;
#pragma unroll
    for (int i = 0; i < KS; ++i) g[i] *= inv;
}

#define SSIM_ACC(MP, MT, E2, T2, PT) do {                                 \
    float _mps = (MP) * (MP), _mts = (MT) * (MT), _mpt = (MP) * (MT);     \
    float _num = (2.f * _mpt + C1F) * (2.f * ((PT) - _mpt) + C2F);        \
    float _den = (_mps + _mts + C1F) *                                    \
                 (((E2) - _mps) + ((T2) - _mts) + C2F);                   \
    ssim_sum += _num * __builtin_amdgcn_rcpf(_den);                       \
} while (0)

// One D-step with literal residue r: dd = dbb + r, dbb = dbase + 11*blk,
// dbase in {-5, 28} (both == 6 mod 11). Plane dd contributes to outputs
// d = dd-5..dd+5 (j = d-dd+5) at slot d%11 = (r+1+j)%11 with weight g[j]
// (Gaussian symmetry). Emit output od = dd-5 from slot es = (r+1)%11,
// then zero es (es belongs next to output dd+6, whose window starts at
// plane dd+1, so zeroing never kills live contributions).
#define STEP_R(r) do {                                                    \
    const int dd = dbb + (r);                                             \
    if ((unsigned)dd < (unsigned)D_DIM) {                                 \
        const float* pp = pb + (size_t)dd * SLICE;                        \
        const float* tt = tb + (size_t)dd * SLICE;                        \
        _Pragma("unroll")                                                 \
        for (int ii = 0; ii < 3; ++ii) {                                  \
            int i = ii * 256 + tid;                                       \
            if (i < HALO * HALO) {                                        \
                int yy = i / HALO, xx = i - yy * HALO;                    \
                int gh = h0 + yy - RAD, gw = w0 + xx - RAD;               \
                float pv = 0.f, tv = 0.f;                                 \
                if ((unsigned)gh < (unsigned)H_DIM &&                     \
                    (unsigned)gw < (unsigned)W_DIM) {                     \
                    int idx = gh * W_DIM + gw;                            \
                    pv = pp[idx]; tv = tt[idx];                           \
                }                                                         \
                sp[yy * SPITCH + xx] = pv;                                \
                st[yy * SPITCH + xx] = tv;                                \
            }                                                             \
        }                                                                 \
        __syncthreads();                                                  \
        if (tid < 208) {                                                  \
            const int row = tid >> 3, xp = tid & 7;                       \
            const int sb = row * SPITCH + 2 * xp;                         \
            float wp[12], wt[12];                                         \
            _Pragma("unroll")                                             \
            for (int k = 0; k < 12; ++k) {                                \
                wp[k] = sp[sb + k]; wt[k] = st[sb + k];                   \
            }                                                             \
            float s00 = 0.f, s01 = 0.f, s10 = 0.f, s11 = 0.f, s20 = 0.f, \
                  s21 = 0.f, s30 = 0.f, s31 = 0.f, s40 = 0.f, s41 = 0.f; \
            _Pragma("unroll")                                             \
            for (int k = 0; k < KS; ++k) {                                \
                float gk = g[k];                                          \
                float p0 = wp[k], p1 = wp[k + 1];                         \
                float t0 = wt[k], t1 = wt[k + 1];                         \
                s00 += gk * p0;      s01 += gk * p1;                      \
                s10 += gk * t0;      s11 += gk * t1;                      \
                s20 += gk * p0 * p0; s21 += gk * p1 * p1;                 \
                s30 += gk * t0 * t0; s31 += gk * t1 * t1;                 \
                s40 += gk * p0 * t0; s41 += gk * p1 * t1;                 \
            }                                                             \
            const int ia = row * IAP + 2 * xp;                            \
            iA[ia]     = make_float4(s00, s10, s20, s30);                 \
            iA[ia + 1] = make_float4(s01, s11, s21, s31);                 \
            *(float2*)&iB[row * IBP + 2 * xp] = make_float2(s40, s41);    \
        }                                                                 \
        __syncthreads();                                                  \
        float v0 = 0.f, v1 = 0.f, v2 = 0.f, v3 = 0.f, v4 = 0.f;          \
        _Pragma("unroll")                                                 \
        for (int k = 0; k < KS; ++k) {                                    \
            float gk = g[k];                                              \
            float4 q = iA[(hy + k) * IAP + hx];                           \
            v0 += gk * q.x; v1 += gk * q.y;                               \
            v2 += gk * q.z; v3 += gk * q.w;                               \
            v4 += gk * iB[(hy + k) * IBP + hx];                           \
        }                                                                 \
        _Pragma("unroll")                                                 \
        for (int j = 0; j < KS; ++j) {                                    \
            const int s = ((r) + 1 + j) % KS;                             \
            const float gj = g[j];                                        \
            a0[s] += gj * v0; a1[s] += gj * v1; a2[s] += gj * v2;         \
            a3[s] += gj * v3; a4[s] += gj * v4;                           \
        }                                                                 \
    }                                                                     \
    {                                                                     \
        const int es = ((r) + 1) % KS;                                    \
        const int od = dd - 5;                                            \
        if ((unsigned)(od - elo) < ecnt) {                                \
            SSIM_ACC(a0[es], a1[es], a2[es], a3[es], a4[es]);             \
        }                                                                 \
        a0[es] = 0.f; a1[es] = 0.f; a2[es] = 0.f;                         \
        a3[es] = 0.f; a4[es] = 0.f;                                       \
    }                                                                     \
} while (0)

__global__ __launch_bounds__(256, 4) void fused_ssim_kernel(
    const float* __restrict__ pred, const float* __restrict__ targ,
    float* __restrict__ partials) {
    __shared__ float sp[HALO * SPITCH];        // 2808 B
    __shared__ float st[HALO * SPITCH];        // 2808 B
    __shared__ float4 iA[HALO * IAP];          // 7072 B (mu_p,mu_t,p2,t2)
    __shared__ float iB[HALO * IBP];           // 1872 B (pt)
    __shared__ float red[4];

    float g[KS];
    make_window(g);

    const int tid = threadIdx.x;
    const int tile = blockIdx.x;              // 0..143
    const int h0 = (tile / 12) * TH;
    const int w0 = (tile % 12) * TW;
    const int seg = blockIdx.y;               // 0: outputs 0..33, 1: 34..63
    const int b   = blockIdx.z;

    const int dbase = seg ? 28 : -5;          // both == 6 (mod 11)
    const int elo   = seg ? 34 : 0;
    const unsigned ecnt = seg ? 30u : 34u;

    const int hy = tid >> 4, hx = tid & 15;

    const float* pb = pred + (size_t)b * VOL;
    const float* tb = targ + (size_t)b * VOL;

    float a0[KS], a1[KS], a2[KS], a3[KS], a4[KS];
#pragma unroll
    for (int s = 0; s < KS; ++s) {
        a0[s] = 0.f; a1[s] = 0.f; a2[s] = 0.f; a3[s] = 0.f; a4[s] = 0.f;
    }
    float ssim_sum = 0.f;

#pragma unroll 1
    for (int blk = 0; blk < 4; ++blk) {
        const int dbb = dbase + 11 * blk;
        STEP_R(0); STEP_R(1); STEP_R(2); STEP_R(3); STEP_R(4); STEP_R(5);
        STEP_R(6); STEP_R(7); STEP_R(8); STEP_R(9); STEP_R(10);
    }

    // ---- block reduction -> one partial per block ----
    float a = ssim_sum;
#pragma unroll
    for (int off = 32; off > 0; off >>= 1) a += __shfl_down(a, off, 64);
    int lane = tid & 63, wv = tid >> 6;
    if (lane == 0) red[wv] = a;
    __syncthreads();
    if (tid == 0) {
        int bid = (blockIdx.z * 2 + blockIdx.y) * 144 + blockIdx.x;
        partials[bid] = red[0] + red[1] + red[2] + red[3];
    }
}

// ---- finalize ----
__global__ __launch_bounds__(256) void finalize_kernel(
    const float* __restrict__ partials, int n, float* __restrict__ out) {
    double a = 0.0;
    for (int i = threadIdx.x; i < n; i += 256) a += (double)partials[i];
#pragma unroll
    for (int off = 32; off > 0; off >>= 1) a += __shfl_down(a, off, 64);
    __shared__ double red[4];
    int lane = threadIdx.x & 63, wv = threadIdx.x >> 6;
    if (lane == 0) red[wv] = a;
    __syncthreads();
    if (threadIdx.x == 0) {
        double s = red[0] + red[1] + red[2] + red[3];
        out[0] = (float)(1.0 - s / (double)((long long)NB * VOL));
    }
}

extern "C" void kernel_launch(void* const* d_in, const int* in_sizes, int n_in,
                              void* d_out, int out_size, void* d_ws, size_t ws_size,
                              hipStream_t stream) {
    const float* pred = (const float*)d_in[0];
    const float* targ = (const float*)d_in[1];
    float* out = (float*)d_out;
    float* partials = (float*)d_ws;           // 1152 floats

    fused_ssim_kernel<<<dim3(144, 2, NB), 256, 0, stream>>>(pred, targ, partials);
    finalize_kernel<<<1, 256, 0, stream>>>(partials, 144 * 2 * NB, out);
}

// Round 10
// 502.625 us; speedup vs baseline: 2.7422x; 2.7422x over previous
//
#include <hip/hip_runtime.h>

// SSIM 3D loss: pred/target f32 [4,1,64,192,192], scalar 1 - mean(ssim_map).
// v9 = v8 with the register-spill fixed:
//   - __launch_bounds__(256) WITHOUT min-waves (the ",4" in v8 capped the
//     allocator at ~128 VGPR and spilled the 55-float D-accumulator to
//     scratch: 3.5 GB WRITE_SIZE, 1307 us).
//   - Gaussian weights as compile-time constants (literal indices ->
//     immediates; no expf preamble, -11 registers).
// Structure: fused kernel, block = 16x16 px tile x D-segment x batch,
// marching along D: stage 26x26 halo -> W-blur (float4 interm) -> H-blur
// into per-thread registers -> 11-slot register accumulator (literal slots)
// -> guarded SSIM emit. Full fp32. finalize sums 1152 partials.

#define D_DIM 64
#define H_DIM 192
#define W_DIM 192
#define SLICE (H_DIM * W_DIM)   // 36864
#define VOL   (D_DIM * SLICE)   // 2359296
#define NB    4
#define KS    11
#define RAD   5
#define TH    16
#define TW    16
#define HALO  26                // TH + 2*RAD
#define SPITCH 27               // staging pitch (floats)
#define IAP   17                // iA pitch (float4)
#define IBP   18                // iB pitch (floats)
#define C1F   (0.01f * 0.01f)
#define C2F   (0.03f * 0.03f)

// 11-tap Gaussian (sigma=1.5), normalized; matches reference to ~1e-7 rel.
__device__ constexpr float GW[KS] = {
    0.001028380f, 0.007598758f, 0.036000773f, 0.109360705f, 0.213005539f,
    0.266011726f,
    0.213005539f, 0.109360705f, 0.036000773f, 0.007598758f, 0.001028380f};

#define SSIM_ACC(MP, MT, E2, T2, PT) do {                                 \
    float _mps = (MP) * (MP), _mts = (MT) * (MT), _mpt = (MP) * (MT);     \
    float _num = (2.f * _mpt + C1F) * (2.f * ((PT) - _mpt) + C2F);        \
    float _den = (_mps + _mts + C1F) *                                    \
                 (((E2) - _mps) + ((T2) - _mts) + C2F);                   \
    ssim_sum += _num * __builtin_amdgcn_rcpf(_den);                       \
} while (0)

// One D-step with literal residue r: dd = dbb + r, dbb = dbase + 11*blk,
// dbase in {-5, 28} (both == 6 mod 11). Plane dd contributes to outputs
// d = dd-5..dd+5 (j = d-dd+5) at slot d%11 = (r+1+j)%11 with weight GW[j]
// (Gaussian symmetry). Emit output od = dd-5 from slot es = (r+1)%11,
// then zero es (es next belongs to output dd+6, whose window starts at
// plane dd+1, so zeroing never kills live contributions).
#define STEP_R(r) do {                                                    \
    const int dd = dbb + (r);                                             \
    if ((unsigned)dd < (unsigned)D_DIM) {                                 \
        const float* pp = pb + (size_t)dd * SLICE;                        \
        const float* tt = tb + (size_t)dd * SLICE;                        \
        _Pragma("unroll")                                                 \
        for (int ii = 0; ii < 3; ++ii) {                                  \
            int i = ii * 256 + tid;                                       \
            if (i < HALO * HALO) {                                        \
                int yy = i / HALO, xx = i - yy * HALO;                    \
                int gh = h0 + yy - RAD, gw = w0 + xx - RAD;               \
                float pv = 0.f, tv = 0.f;                                 \
                if ((unsigned)gh < (unsigned)H_DIM &&                     \
                    (unsigned)gw < (unsigned)W_DIM) {                     \
                    int idx = gh * W_DIM + gw;                            \
                    pv = pp[idx]; tv = tt[idx];                           \
                }                                                         \
                sp[yy * SPITCH + xx] = pv;                                \
                st[yy * SPITCH + xx] = tv;                                \
            }                                                             \
        }                                                                 \
        __syncthreads();                                                  \
        if (tid < 208) {                                                  \
            const int row = tid >> 3, xp = tid & 7;                       \
            const int sb = row * SPITCH + 2 * xp;                         \
            float wp[12], wt[12];                                         \
            _Pragma("unroll")                                             \
            for (int k = 0; k < 12; ++k) {                                \
                wp[k] = sp[sb + k]; wt[k] = st[sb + k];                   \
            }                                                             \
            float s00 = 0.f, s01 = 0.f, s10 = 0.f, s11 = 0.f, s20 = 0.f, \
                  s21 = 0.f, s30 = 0.f, s31 = 0.f, s40 = 0.f, s41 = 0.f; \
            _Pragma("unroll")                                             \
            for (int k = 0; k < KS; ++k) {                                \
                float gk = GW[k];                                         \
                float p0 = wp[k], p1 = wp[k + 1];                         \
                float t0 = wt[k], t1 = wt[k + 1];                         \
                s00 += gk * p0;      s01 += gk * p1;                      \
                s10 += gk * t0;      s11 += gk * t1;                      \
                s20 += gk * p0 * p0; s21 += gk * p1 * p1;                 \
                s30 += gk * t0 * t0; s31 += gk * t1 * t1;                 \
                s40 += gk * p0 * t0; s41 += gk * p1 * t1;                 \
            }                                                             \
            const int ia = row * IAP + 2 * xp;                            \
            iA[ia]     = make_float4(s00, s10, s20, s30);                 \
            iA[ia + 1] = make_float4(s01, s11, s21, s31);                 \
            *(float2*)&iB[row * IBP + 2 * xp] = make_float2(s40, s41);    \
        }                                                                 \
        __syncthreads();                                                  \
        float v0 = 0.f, v1 = 0.f, v2 = 0.f, v3 = 0.f, v4 = 0.f;          \
        _Pragma("unroll")                                                 \
        for (int k = 0; k < KS; ++k) {                                    \
            float gk = GW[k];                                             \
            float4 q = iA[(hy + k) * IAP + hx];                           \
            v0 += gk * q.x; v1 += gk * q.y;                               \
            v2 += gk * q.z; v3 += gk * q.w;                               \
            v4 += gk * iB[(hy + k) * IBP + hx];                           \
        }                                                                 \
        _Pragma("unroll")                                                 \
        for (int j = 0; j < KS; ++j) {                                    \
            const int s = ((r) + 1 + j) % KS;                             \
            const float gj = GW[j];                                       \
            a0[s] += gj * v0; a1[s] += gj * v1; a2[s] += gj * v2;         \
            a3[s] += gj * v3; a4[s] += gj * v4;                           \
        }                                                                 \
    }                                                                     \
    {                                                                     \
        const int es = ((r) + 1) % KS;                                    \
        const int od = dd - 5;                                            \
        if ((unsigned)(od - elo) < ecnt) {                                \
            SSIM_ACC(a0[es], a1[es], a2[es], a3[es], a4[es]);             \
        }                                                                 \
        a0[es] = 0.f; a1[es] = 0.f; a2[es] = 0.f;                         \
        a3[es] = 0.f; a4[es] = 0.f;                                       \
    }                                                                     \
} while (0)

__global__ __launch_bounds__(256) void fused_ssim_kernel(
    const float* __restrict__ pred, const float* __restrict__ targ,
    float* __restrict__ partials) {
    __shared__ float sp[HALO * SPITCH];        // 2808 B
    __shared__ float st[HALO * SPITCH];        // 2808 B
    __shared__ float4 iA[HALO * IAP];          // 7072 B (mu_p,mu_t,p2,t2)
    __shared__ float iB[HALO * IBP];           // 1872 B (pt)
    __shared__ float red[4];

    const int tid = threadIdx.x;
    const int tile = blockIdx.x;              // 0..143
    const int h0 = (tile / 12) * TH;
    const int w0 = (tile % 12) * TW;
    const int seg = blockIdx.y;               // 0: outputs 0..33, 1: 34..63
    const int b   = blockIdx.z;

    const int dbase = seg ? 28 : -5;          // both == 6 (mod 11)
    const int elo   = seg ? 34 : 0;
    const unsigned ecnt = seg ? 30u : 34u;

    const int hy = tid >> 4, hx = tid & 15;

    const float* pb = pred + (size_t)b * VOL;
    const float* tb = targ + (size_t)b * VOL;

    float a0[KS], a1[KS], a2[KS], a3[KS], a4[KS];
#pragma unroll
    for (int s = 0; s < KS; ++s) {
        a0[s] = 0.f; a1[s] = 0.f; a2[s] = 0.f; a3[s] = 0.f; a4[s] = 0.f;
    }
    float ssim_sum = 0.f;

#pragma unroll 1
    for (int blk = 0; blk < 4; ++blk) {
        const int dbb = dbase + 11 * blk;
        STEP_R(0); STEP_R(1); STEP_R(2); STEP_R(3); STEP_R(4); STEP_R(5);
        STEP_R(6); STEP_R(7); STEP_R(8); STEP_R(9); STEP_R(10);
    }

    // ---- block reduction -> one partial per block ----
    float a = ssim_sum;
#pragma unroll
    for (int off = 32; off > 0; off >>= 1) a += __shfl_down(a, off, 64);
    int lane = tid & 63, wv = tid >> 6;
    if (lane == 0) red[wv] = a;
    __syncthreads();
    if (tid == 0) {
        int bid = (blockIdx.z * 2 + blockIdx.y) * 144 + blockIdx.x;
        partials[bid] = red[0] + red[1] + red[2] + red[3];
    }
}

// ---- finalize ----
__global__ __launch_bounds__(256) void finalize_kernel(
    const float* __restrict__ partials, int n, float* __restrict__ out) {
    double a = 0.0;
    for (int i = threadIdx.x; i < n; i += 256) a += (double)partials[i];
#pragma unroll
    for (int off = 32; off > 0; off >>= 1) a += __shfl_down(a, off, 64);
    __shared__ double red[4];
    int lane = threadIdx.x & 63, wv = threadIdx.x >> 6;
    if (lane == 0) red[wv] = a;
    __syncthreads();
    if (threadIdx.x == 0) {
        double s = red[0] + red[1] + red[2] + red[3];
        out[0] = (float)(1.0 - s / (double)((long long)NB * VOL));
    }
}

extern "C" void kernel_launch(void* const* d_in, const int* in_sizes, int n_in,
                              void* d_out, int out_size, void* d_ws, size_t ws_size,
                              hipStream_t stream) {
    const float* pred = (const float*)d_in[0];
    const float* targ = (const float*)d_in[1];
    float* out = (float*)d_out;
    float* partials = (float*)d_ws;           // 1152 floats

    fused_ssim_kernel<<<dim3(144, 2, NB), 256, 0, stream>>>(pred, targ, partials);
    finalize_kernel<<<1, 256, 0, stream>>>(partials, 144 * 2 * NB, out);
}

// Round 11
// 213.646 us; speedup vs baseline: 6.4512x; 2.3526x over previous
//
#include <hip/hip_runtime.h>

// SSIM 3D loss: pred/target f32 [4,1,64,192,192], scalar 1 - mean(ssim_map).
// v10: A & C = v5b verbatim (best measured: A=89us).
//      B = v5b's modular sliding window + 4-deep raw-bits prefetch:
//        4 rotating uint2/u32 reg buffers hold planes q..q+3 in flight;
//        per round: commit buf q%4 -> fp32 window (literal slot), issue
//        loads for plane q+4, EMIT. ~8 loads in flight per wave hides
//        L3/HBM latency (v5b B was MLP-starved: 1 round = 1 full latency).

#define D_DIM 64
#define H_DIM 192
#define W_DIM 192
#define SLICE (H_DIM * W_DIM)   // 36864
#define VOL   (D_DIM * SLICE)   // 2359296
#define NB    4
#define KS    11
#define RAD   5
#define TH    32
#define TW    48
#define HT    (TH + 2 * RAD)    // 42 halo rows
#define WTT   (TW + 2 * RAD)    // 58 halo cols
#define SPITCH 59               // staging pitch (fp32)
#define IP2   48                // interm pitch (fp16 halves)
#define IPF2  (HT * IP2)        // 2016 halves per field
#define C1F   (0.01f * 0.01f)
#define C2F   (0.03f * 0.03f)

typedef _Float16 h2v __attribute__((ext_vector_type(2)));

__device__ __forceinline__ void make_window(float* g) {
    float s = 0.f;
#pragma unroll
    for (int i = 0; i < KS; ++i) {
        float c = (float)(i - RAD);
        g[i] = expf(-(c * c) * (1.0f / 4.5f));  // 2*sigma^2 = 4.5
        s += g[i];
    }
    float inv = 1.0f / s;
#pragma unroll
    for (int i = 0; i < KS; ++i) g[i] *= inv;
}

// ---- Kernel A: W+H blur of 5 derived fields for one (b,d) slice tile ----
__global__ __launch_bounds__(256) void hw_blur_kernel(
    const float* __restrict__ pred, const float* __restrict__ targ,
    uint2* __restrict__ Xg, unsigned short* __restrict__ Yg, int b0) {
    __shared__ union U {
        float stage[2 * HT * SPITCH];            // 19824 B: sp | st
        unsigned short obuf[5 * TH * TW];        // 15360 B, reused after W
    } u;
    __shared__ _Float16 interm2[5 * IPF2];       // 20160 B
    float* sp = u.stage;
    float* st = u.stage + HT * SPITCH;

    float g[KS];
    make_window(g);

    const int tid = threadIdx.x;
    const int d    = blockIdx.y;
    const int tile = blockIdx.x;              // 0..23
    const int h0 = (tile >> 2) * TH;          // 6 tiles in H
    const int w0 = (tile & 3) * TW;           // 4 tiles in W
    const int bl = blockIdx.z;

    const int in_base = (b0 + bl) * VOL + d * SLICE;

    // ---- Stage p/t halo tiles (zero-padded at H/W edges and pad col) ----
    for (int i = tid; i < HT * SPITCH; i += 256) {
        int y = i / SPITCH, x = i - y * SPITCH;
        int gh = h0 + y - RAD, gw = w0 + x - RAD;
        float pv = 0.f, tv = 0.f;
        if (x < WTT && (unsigned)gh < (unsigned)H_DIM && (unsigned)gw < (unsigned)W_DIM) {
            int idx = in_base + gh * W_DIM + gw;
            pv = pred[idx];
            tv = targ[idx];
        }
        sp[i] = pv;
        st[i] = tv;
    }
    __syncthreads();

    // ---- Phase W: register-window blur along W, derive 5 fields ----
    // 252 tasks: y in [0,42) halo rows x 6 segments of 8 outputs
    if (tid < 252) {
        const int y = tid / 6;
        const int x0 = (tid % 6) * 8;
        float wp[18], wt[18];
#pragma unroll
        for (int k = 0; k < 18; ++k) {
            wp[k] = sp[y * SPITCH + x0 + k];
            wt[k] = st[y * SPITCH + x0 + k];
        }
#pragma unroll
        for (int o = 0; o < 8; ++o) {
            float s0 = 0.f, s1 = 0.f, s2 = 0.f, s3 = 0.f, s4 = 0.f;
#pragma unroll
            for (int k = 0; k < KS; ++k) {
                float pv = wp[o + k], tv = wt[o + k], gk = g[k];
                s0 += gk * pv;
                s1 += gk * tv;
                s2 += gk * pv * pv;
                s3 += gk * tv * tv;
                s4 += gk * pv * tv;
            }
            int idx = y * IP2 + x0 + o;
            interm2[0 * IPF2 + idx] = (_Float16)s0;
            interm2[1 * IPF2 + idx] = (_Float16)s1;
            interm2[2 * IPF2 + idx] = (_Float16)s2;
            interm2[3 * IPF2 + idx] = (_Float16)s3;
            interm2[4 * IPF2 + idx] = (_Float16)s4;
        }
    }
    __syncthreads();

    // ---- Phase H: accumulator-trick blur along H -> fp16 into LDS obuf ----
    // Row yy feeds outputs y = yy-10..yy: slot (yy+m+1)%11 gets g[10-m].
    // Ramp-in guard: skip m < 10-yy for yy < 10 (outputs y < 0).
    // 240 tasks: field f in [0,5) x column x in [0,48)
    if (tid < 240) {
        const int f = tid / TW;
        const int x = tid % TW;
        const _Float16* col = interm2 + f * IPF2 + x;
        unsigned short* ob = u.obuf + f * (TH * TW) + x;
        float acc[KS];
#pragma unroll
        for (int s = 0; s < KS; ++s) acc[s] = 0.f;
#pragma unroll
        for (int yy = 0; yy < HT; ++yy) {
            float v = (float)col[yy * IP2];
#pragma unroll
            for (int m = 0; m < KS; ++m) {
                if (yy < 10 && m < 10 - yy) continue;   // folds at compile time
                acc[(yy + m + 1) % KS] += g[10 - m] * v;
            }
            if (yy >= 10) {
                const int y = yy - 10;
                const int s = (yy + 1) % KS;
                _Float16 h = (_Float16)acc[s];
                ob[y * TW] = *(unsigned short*)&h;
                acc[s] = 0.f;
            }
        }
    }
    __syncthreads();

    // ---- Store phase: gather 4 fields/px -> 8B X stores; pt -> 2B Y ----
    const size_t pl_base = (size_t)(bl * D_DIM + d) * SLICE;
#pragma unroll
    for (int it = 0; it < 6; ++it) {              // 1536 px / 256 threads
        int px = it * 256 + tid;
        int y = px / TW, x = px - y * TW;
        unsigned a0 = u.obuf[0 * (TH * TW) + px];
        unsigned a1 = u.obuf[1 * (TH * TW) + px];
        unsigned a2 = u.obuf[2 * (TH * TW) + px];
        unsigned a3 = u.obuf[3 * (TH * TW) + px];
        unsigned a4 = u.obuf[4 * (TH * TW) + px];
        size_t gi = pl_base + (size_t)(h0 + y) * W_DIM + (w0 + x);
        Xg[gi] = make_uint2(a0 | (a1 << 16), a2 | (a3 << 16));
        Yg[gi] = (unsigned short)a4;
    }
}

// ================= Kernel B: D blur + SSIM + partial sums =================
// Modular sliding window (slot = plane%11) + 4-deep raw prefetch buffers.

// immediate load+commit (initial window fill; loads batch-issue)
#define LOADP(s, q) do {                                                  \
    const int _o = (q) * SLICE;                                           \
    uint2 _r = xg[_o];                                                    \
    h2v _l = __builtin_bit_cast(h2v, _r.x);                               \
    h2v _h = __builtin_bit_cast(h2v, _r.y);                               \
    w0[s] = (float)_l[0]; w1[s] = (float)_l[1];                           \
    w2[s] = (float)_h[0]; w3[s] = (float)_h[1];                           \
    w4[s] = (float)__builtin_bit_cast(_Float16, (unsigned short)yg[(q) * SLICE]); \
} while (0)

// prefetch plane q into raw buffer i
#define PRE(i, q) do {                                                    \
    xr##i = xg[(q) * SLICE];                                              \
    yr##i = yg[(q) * SLICE];                                              \
} while (0)

// commit raw buffer i into window slot s
#define CMT(s, i) do {                                                    \
    h2v _l = __builtin_bit_cast(h2v, xr##i.x);                            \
    h2v _h = __builtin_bit_cast(h2v, xr##i.y);                            \
    w0[s] = (float)_l[0]; w1[s] = (float)_l[1];                           \
    w2[s] = (float)_h[0]; w3[s] = (float)_h[1];                           \
    w4[s] = (float)__builtin_bit_cast(_Float16, (unsigned short)yr##i);   \
} while (0)

#define SSIM_ACC(MP, MT, E2, T2, PT) do {                                 \
    float _mps = (MP) * (MP), _mts = (MT) * (MT), _mpt = (MP) * (MT);     \
    float _num = (2.f * _mpt + C1F) * (2.f * ((PT) - _mpt) + C2F);        \
    float _den = (_mps + _mts + C1F) *                                    \
                 (((E2) - _mps) + ((T2) - _mts) + C2F);                   \
    ssim_sum += _num * __builtin_amdgcn_rcpf(_den);                       \
} while (0)

// emit output d with r = (d-6) mod 11: window slots (1+r+j)%11, j=0..JHI
#define EMIT_W(r, JHI) do {                                               \
    float _mp = 0.f, _mt = 0.f, _e2 = 0.f, _t2 = 0.f, _pt = 0.f;          \
    _Pragma("unroll")                                                     \
    for (int _j = 0; _j <= (JHI); ++_j) {                                 \
        const int _s = (1 + (r) + _j) % 11; const float _g = g[_j];       \
        _mp += _g * w0[_s]; _mt += _g * w1[_s]; _e2 += _g * w2[_s];       \
        _t2 += _g * w3[_s]; _pt += _g * w4[_s];                           \
    }                                                                     \
    SSIM_ACC(_mp, _mt, _e2, _t2, _pt);                                    \
} while (0)

// ramp-in emit for output d in [0,5]: planes 0..d+5 at slot = plane
#define EMIT_IN(d) do {                                                   \
    float _mp = 0.f, _mt = 0.f, _e2 = 0.f, _t2 = 0.f, _pt = 0.f;          \
    _Pragma("unroll")                                                     \
    for (int _j = 5 - (d); _j < 11; ++_j) {                               \
        const int _s = (d) - 5 + _j; const float _g = g[_j];              \
        _mp += _g * w0[_s]; _mt += _g * w1[_s]; _e2 += _g * w2[_s];       \
        _t2 += _g * w3[_s]; _pt += _g * w4[_s];                           \
    }                                                                     \
    SSIM_ACC(_mp, _mt, _e2, _t2, _pt);                                    \
} while (0)

// steady-state round: commit buf i to slot r, prefetch plane qn into buf i, emit
#define RND(r, i, qn)  do { CMT(r, i); PRE(i, qn); EMIT_W(r, 10); } while (0)
#define RNDL(r, i)     do { CMT(r, i); EMIT_W(r, 10); } while (0)   // no prefetch

__global__ __launch_bounds__(256) void dblur_ssim_kernel(
    const uint2* __restrict__ Xg, const unsigned short* __restrict__ Yg,
    float* __restrict__ partials) {
    float g[KS];
    make_window(g);

    const int tid = threadIdx.x;
    const int bl = blockIdx.x / 144;                 // local batch
    const int hw = (blockIdx.x % 144) * 256 + tid;   // 0..SLICE-1
    const int cb = bl * VOL + hw;
    const uint2* xg = Xg + cb;
    const unsigned short* yg = Yg + cb;

    float w0[KS], w1[KS], w2[KS], w3[KS], w4[KS];
    uint2 xr0, xr1, xr2, xr3;
    unsigned yr0, yr1, yr2, yr3;
    float ssim_sum = 0.f;

    if (blockIdx.y == 0) {
        // ---- outputs d = 0..31, planes 0..36 ----
        LOADP(0, 0); LOADP(1, 1); LOADP(2, 2); LOADP(3, 3); LOADP(4, 4);
        LOADP(5, 5); LOADP(6, 6); LOADP(7, 7); LOADP(8, 8); LOADP(9, 9);
        LOADP(10, 10);
        PRE(3, 11); PRE(0, 12); PRE(1, 13); PRE(2, 14);
        EMIT_IN(0); EMIT_IN(1); EMIT_IN(2); EMIT_IN(3); EMIT_IN(4); EMIT_IN(5);
        RND(0, 3, 15);  RND(1, 0, 16);  RND(2, 1, 17);  RND(3, 2, 18);   // q=11..14
        RND(4, 3, 19);  RND(5, 0, 20);  RND(6, 1, 21);  RND(7, 2, 22);   // q=15..18
        RND(8, 3, 23);  RND(9, 0, 24);  RND(10, 1, 25); RND(0, 2, 26);   // q=19..22
        RND(1, 3, 27);  RND(2, 0, 28);  RND(3, 1, 29);  RND(4, 2, 30);   // q=23..26
        RND(5, 3, 31);  RND(6, 0, 32);  RND(7, 1, 33);  RND(8, 2, 34);   // q=27..30
        RND(9, 3, 35);  RND(10, 0, 36);                                  // q=31..32
        RNDL(0, 1); RNDL(1, 2); RNDL(2, 3); RNDL(3, 0);                  // q=33..36
    } else {
        // ---- outputs d = 32..63, planes 27..63 ----
        LOADP(5, 27); LOADP(6, 28); LOADP(7, 29); LOADP(8, 30); LOADP(9, 31);
        LOADP(10, 32); LOADP(0, 33); LOADP(1, 34); LOADP(2, 35); LOADP(3, 36);
        LOADP(4, 37);
        PRE(2, 38); PRE(3, 39); PRE(0, 40); PRE(1, 41);
        EMIT_W(4, 10);                                // d = 32 (planes 27..37)
        RND(5, 2, 42);  RND(6, 3, 43);  RND(7, 0, 44);  RND(8, 1, 45);   // q=38..41
        RND(9, 2, 46);  RND(10, 3, 47); RND(0, 0, 48);  RND(1, 1, 49);   // q=42..45
        RND(2, 2, 50);  RND(3, 3, 51);  RND(4, 0, 52);  RND(5, 1, 53);   // q=46..49
        RND(6, 2, 54);  RND(7, 3, 55);  RND(8, 0, 56);  RND(9, 1, 57);   // q=50..53
        RND(10, 2, 58); RND(0, 3, 59);  RND(1, 0, 60);  RND(2, 1, 61);   // q=54..57
        RND(3, 2, 62);  RND(4, 3, 63);                                   // q=58..59
        RNDL(5, 0); RNDL(6, 1); RNDL(7, 2); RNDL(8, 3);                  // q=60..63
        // ramp-out d = 59..63 (truncated windows, no loads)
        EMIT_W(9, 9); EMIT_W(10, 8); EMIT_W(11, 7); EMIT_W(12, 6); EMIT_W(13, 5);
    }

    // block reduction
    float a = ssim_sum;
#pragma unroll
    for (int off = 32; off > 0; off >>= 1) a += __shfl_down(a, off, 64);
    __shared__ float red[4];
    int lane = tid & 63, wv = tid >> 6;
    if (lane == 0) red[wv] = a;
    __syncthreads();
    if (tid == 0)
        partials[blockIdx.y * gridDim.x + blockIdx.x] =
            red[0] + red[1] + red[2] + red[3];
}

// ---- Kernel C: final reduction ----
__global__ __launch_bounds__(256) void finalize_kernel(
    const float* __restrict__ partials, int n, float* __restrict__ out) {
    double a = 0.0;
    for (int i = threadIdx.x; i < n; i += 256) a += (double)partials[i];
#pragma unroll
    for (int off = 32; off > 0; off >>= 1) a += __shfl_down(a, off, 64);
    __shared__ double red[4];
    int lane = threadIdx.x & 63, wv = threadIdx.x >> 6;
    if (lane == 0) red[wv] = a;
    __syncthreads();
    if (threadIdx.x == 0) {
        double s = red[0] + red[1] + red[2] + red[3];
        out[0] = (float)(1.0 - s / (double)((long long)NB * VOL));
    }
}

extern "C" void kernel_launch(void* const* d_in, const int* in_sizes, int n_in,
                              void* d_out, int out_size, void* d_ws, size_t ws_size,
                              hipStream_t stream) {
    const float* pred = (const float*)d_in[0];
    const float* targ = (const float*)d_in[1];
    float* out = (float*)d_out;

    // batches per chunk G in {4,2,1}: X (8B/px) + Y (2B/px) + partials
    int G = 4;
    while (G > 1 && (size_t)G * VOL * 10 + 8192 > ws_size) G >>= 1;

    uint2* Xg = (uint2*)d_ws;
    unsigned short* Yg = (unsigned short*)((char*)d_ws + (size_t)G * VOL * 8);
    float* partials = (float*)((char*)d_ws + (size_t)G * VOL * 10);
    const int bpc = G * 144;                   // dblur blocks per (chunk, half)
    const int nchunks = NB / G;

    for (int c = 0; c < nchunks; ++c) {
        hw_blur_kernel<<<dim3(24, D_DIM, G), 256, 0, stream>>>(
            pred, targ, Xg, Yg, c * G);
        dblur_ssim_kernel<<<dim3(bpc, 2), 256, 0, stream>>>(
            Xg, Yg, partials + c * 2 * bpc);
    }
    finalize_kernel<<<1, 256, 0, stream>>>(partials, NB * 288, out);
}